// Round 3
// baseline (650.834 us; speedup 1.0000x reference)
//
#include <hip/hip_runtime.h>
#include <hip/hip_fp16.h>

// Problem: B=4, S=2048, H=8, E=64. BH=32 heads total.
// Pipeline: proj (q,k = x@W^T+b, [b,h,s,e] f16 hi+lo; v -> TRANSPOSED [b,h,e,s]) ->
//           maskgen (jax threefry2x32 partitionable, 1 elem/lane + ballot) ->
//           attn (two-pass flash, register-prefetch pipelined staging).
// Workspace layout (needs 64 MiB):
//   Qh 0, Ql 8M, Kh 16M, Kl 24M, Vth 32M, Vtl 40M, mask 48M..64M

typedef _Float16 f16;
typedef _Float16 f16x4 __attribute__((ext_vector_type(4)));
typedef _Float16 f16x8 __attribute__((ext_vector_type(8)));
typedef float f32x4v __attribute__((ext_vector_type(4)));
typedef unsigned int u32;
typedef unsigned long long u64;

// ---------------- projection: out[f] = sum_e x[e]*W[f][e] + b[f] ----------------
// TRANSP=false: store [b,h,s,e] (Q,K). TRANSP=true: store [b,h,e,s] (V).
template<bool TRANSP>
__global__ __launch_bounds__(256) void proj_kernel(
    const float* __restrict__ X, const float* __restrict__ W,
    const float* __restrict__ bias,
    f16* __restrict__ Oh, f16* __restrict__ Ol)
{
    __shared__ __align__(16) float Wl[64 * 68];
    __shared__ __align__(16) float Xl[128 * 68];
    const int t = threadIdx.x;
    const int tb = blockIdx.x * 128;

    for (int c = t; c < 1024; c += 256) {          // W: 64x64 floats
        int f = c >> 4, e4 = (c & 15) << 2;
        *(float4*)&Wl[f * 68 + e4] = *(const float4*)(W + f * 64 + e4);
    }
    for (int c = t; c < 2048; c += 256) {          // X: 128x64 floats
        int tok = c >> 4, e4 = (c & 15) << 2;
        *(float4*)&Xl[tok * 68 + e4] = *(const float4*)(X + (size_t)(tb + tok) * 64 + e4);
    }
    __syncthreads();

    const int tx = t & 15;     // token lane
    const int ty = t >> 4;     // f group
    const int f0 = ty * 4;

    float acc[8][4];
#pragma unroll
    for (int i = 0; i < 8; ++i)
#pragma unroll
        for (int j = 0; j < 4; ++j) acc[i][j] = bias[f0 + j];

    for (int e = 0; e < 64; e += 4) {
        float4 wv[4];
#pragma unroll
        for (int j = 0; j < 4; ++j) wv[j] = *(float4*)&Wl[(f0 + j) * 68 + e];
#pragma unroll
        for (int i = 0; i < 8; ++i) {
            float4 xv = *(float4*)&Xl[(tx + 16 * i) * 68 + e];
#pragma unroll
            for (int j = 0; j < 4; ++j)
                acc[i][j] += xv.x * wv[j].x + xv.y * wv[j].y + xv.z * wv[j].z + xv.w * wv[j].w;
        }
    }

#pragma unroll
    for (int i = 0; i < 8; ++i) {
        int tin = tb + tx + 16 * i;
        int h  = tin & 7;          // H=8 fastest in input
        int bs = tin >> 3;
        int b  = bs >> 11;         // S=2048
        int s  = bs & 2047;
        f16x4 hv, lv;
#pragma unroll
        for (int j = 0; j < 4; ++j) {
            float a = acc[i][j];
            f16 hh = (f16)a;
            hv[j] = hh;
            lv[j] = (f16)(a - (float)hh);   // exact residual -> q to ~2^-22
        }
        if (!TRANSP) {
            size_t o = ((size_t)(b * 8 + h) * 2048 + s) * 64 + f0;   // [b,h,s,e]
            *(f16x4*)(Oh + o) = hv;
            *(f16x4*)(Ol + o) = lv;
        } else {
            size_t o = ((size_t)(b * 8 + h) * 64 + f0) * 2048 + s;   // [b,h,e,s]
#pragma unroll
            for (int j = 0; j < 4; ++j) {
                Oh[o + (size_t)j * 2048] = hv[j];
                Ol[o + (size_t)j * 2048] = lv[j];
            }
        }
    }
}

// ---------------- dropout mask: jax threefry2x32, PARTITIONABLE path ----------------
// per flat index i over [B,H,S,S]: (b1,b2) = threefry2x32((0,42),(0,i)); bits=b1^b2;
// keep <=> bits < 0xE6666600. One element per lane, 2 chains/thread, ballot-packed.
__global__ __launch_bounds__(256) void maskgen_kernel(u32* __restrict__ mask)
{
    const u32 wid  = (blockIdx.x * 256u + threadIdx.x) >> 6;   // global wave id
    const int lane = threadIdx.x & 63;
    const u32 ks1 = 42u, ks2 = 0x1BD11BF0u;                    // ks0=0; 0x1BD11BDA^0^42
    const u32 eA = wid * 128u + (u32)lane;                     // chain A element
    // two interleaved threefry chains for ILP
    u32 a0 = 0u, a1 = eA + ks1;
    u32 b0 = 0u, b1 = eA + 64u + ks1;
#define QR2(r) \
    a0 += a1; b0 += b1; \
    a1 = __builtin_rotateleft32(a1, r); b1 = __builtin_rotateleft32(b1, r); \
    a1 ^= a0; b1 ^= b0;
#define TF4(p,q,r,s) QR2(p) QR2(q) QR2(r) QR2(s)
    TF4(13,15,26,6)   a0 += ks1; a1 += ks2 + 1u;  b0 += ks1; b1 += ks2 + 1u;
    TF4(17,29,16,24)  a0 += ks2; a1 += 2u;        b0 += ks2; b1 += 2u;
    TF4(13,15,26,6)               a1 += ks1 + 3u;             b1 += ks1 + 3u;
    TF4(17,29,16,24)  a0 += ks1; a1 += ks2 + 4u;  b0 += ks1; b1 += ks2 + 4u;
    TF4(13,15,26,6)   a0 += ks2; a1 += 5u;        b0 += ks2; b1 += 5u;
#undef TF4
#undef QR2
    u64 bitsA = __ballot((a0 ^ a1) < 0xE6666600u);   // flat 128*wid + 0..63
    u64 bitsB = __ballot((b0 ^ b1) < 0xE6666600u);   // flat 128*wid + 64..127
    if (lane == 0) {
        u64* m64 = (u64*)mask;
        m64[wid * 2u]      = bitsA;
        m64[wid * 2u + 1u] = bitsB;
    }
}

// ---------------- attention ----------------
// grid (16, 32): x = 128-row Q tile, y = bh. 4 waves x 32 rows.
// MFMA 16x16x32 f16. A-layout: A[m=lane&15][k=(lane>>4)*8+j];
// B-layout: B[k=(lane>>4)*8+j][n=lane&15]; C: row=(lane>>4)*4+r, col=lane&15.
// Register-prefetch pipeline: fetch kt+1 into VGPRs while computing kt.
__global__ __launch_bounds__(256, 2) void attn_kernel(
    const f16* __restrict__ Qh, const f16* __restrict__ Ql,
    const f16* __restrict__ Kh, const f16* __restrict__ Kl,
    const f16* __restrict__ Vth, const f16* __restrict__ Vtl,
    const u32* __restrict__ mask, float* __restrict__ out)
{
    constexpr int LDK = 88;   // half stride: 176 B rows (16B aligned)
    __shared__ __align__(16) f16 kh_l[64 * LDK];
    __shared__ __align__(16) f16 kl_l[64 * LDK];
    __shared__ __align__(16) f16 vh_l[64 * LDK];   // [e][s] (global already transposed)
    __shared__ __align__(16) f16 vl_l[64 * LDK];
    __shared__ __align__(16) f16 p_l[4][32 * LDK]; // per-wave P tile
    __shared__ u32 m_l[256];                       // 128 q-rows x 2 words

    const int t = threadIdx.x;
    const int w = t >> 6;
    const int lane = t & 63;
    const int lrow = lane & 15;
    const int kg = lane >> 4;
    const int qt = blockIdx.x;
    const int bh = blockIdx.y;

    // persistent Q fragments (hi/lo), 2 m-tiles x 2 k-steps
    f16x8 qh[2][2], ql[2][2];
#pragma unroll
    for (int mt = 0; mt < 2; ++mt) {
        size_t rowg = (size_t)bh * 2048 + qt * 128 + w * 32 + mt * 16 + lrow;
        const f16* ph = Qh + rowg * 64 + kg * 8;
        const f16* pl = Ql + rowg * 64 + kg * 8;
        qh[mt][0] = *(const f16x8*)(ph);
        qh[mt][1] = *(const f16x8*)(ph + 32);
        ql[mt][0] = *(const f16x8*)(pl);
        ql[mt][1] = *(const f16x8*)(pl + 32);
    }

    const size_t kbase = (size_t)bh * 2048 * 64;   // same footprint for K and Vt

    // ---- prefetch registers ----
    uint4 pk[2][2];   // [c-iter][hi/lo]
    uint4 pv[2][2];
    u32   pm;

    auto fetch_k = [&](int kt) {
#pragma unroll
        for (int ci = 0; ci < 2; ++ci) {
            int c = t + 256 * ci;
            int r = c >> 3, c8 = (c & 7) << 3;
            size_t g = kbase + (size_t)(kt * 64 + r) * 64 + c8;
            pk[ci][0] = *(const uint4*)(Kh + g);
            pk[ci][1] = *(const uint4*)(Kl + g);
        }
    };
    auto commit_k = [&]() {
#pragma unroll
        for (int ci = 0; ci < 2; ++ci) {
            int c = t + 256 * ci;
            int r = c >> 3, c8 = (c & 7) << 3;
            *(uint4*)&kh_l[r * LDK + c8] = pk[ci][0];
            *(uint4*)&kl_l[r * LDK + c8] = pk[ci][1];
        }
    };
    auto fetch_v = [&](int kt) {          // global [e][s]: row e, cols kt*64+...
#pragma unroll
        for (int ci = 0; ci < 2; ++ci) {
            int c = t + 256 * ci;
            int e = c >> 3, c8 = (c & 7) << 3;
            size_t g = kbase + (size_t)e * 2048 + kt * 64 + c8;
            pv[ci][0] = *(const uint4*)(Vth + g);
            pv[ci][1] = *(const uint4*)(Vtl + g);
        }
    };
    auto commit_v = [&]() {
#pragma unroll
        for (int ci = 0; ci < 2; ++ci) {
            int c = t + 256 * ci;
            int e = c >> 3, c8 = (c & 7) << 3;
            *(uint4*)&vh_l[e * LDK + c8] = pv[ci][0];
            *(uint4*)&vl_l[e * LDK + c8] = pv[ci][1];
        }
    };
    auto fetch_m = [&](int kt) {
        pm = mask[(size_t)bh * 131072 + (size_t)(qt * 128 + (t >> 1)) * 64 + kt * 2 + (t & 1)];
    };

    // identical score computation for both passes (bit-identical chain order)
    auto compute_S = [&](f32x4v sfr[2][4]) {
#pragma unroll
        for (int mt = 0; mt < 2; ++mt)
#pragma unroll
            for (int n = 0; n < 4; ++n)
                sfr[mt][n] = f32x4v{0.f, 0.f, 0.f, 0.f};
#pragma unroll
        for (int n = 0; n < 4; ++n) {
#pragma unroll
            for (int ks = 0; ks < 2; ++ks) {
                const int off = (n * 16 + lrow) * LDK + ks * 32 + kg * 8;
                f16x8 bhf = *(const f16x8*)&kh_l[off];
                f16x8 blf = *(const f16x8*)&kl_l[off];
#pragma unroll
                for (int mt = 0; mt < 2; ++mt) {
                    sfr[mt][n] = __builtin_amdgcn_mfma_f32_16x16x32_f16(qh[mt][ks], bhf, sfr[mt][n], 0, 0, 0);
                    sfr[mt][n] = __builtin_amdgcn_mfma_f32_16x16x32_f16(ql[mt][ks], bhf, sfr[mt][n], 0, 0, 0);
                    sfr[mt][n] = __builtin_amdgcn_mfma_f32_16x16x32_f16(qh[mt][ks], blf, sfr[mt][n], 0, 0, 0);
                }
            }
        }
    };

    // ---- pass A: row sums l = sum exp(s - 8) (fixed shift; cancels in e/l) ----
    float lsum[2][4] = {{0.f, 0.f, 0.f, 0.f}, {0.f, 0.f, 0.f, 0.f}};
    fetch_k(0);
    for (int kt = 0; kt < 32; ++kt) {
        __syncthreads();           // LDS consumed -> writable
        commit_k();
        __syncthreads();           // LDS ready
        if (kt < 31) fetch_k(kt + 1);   // latency hidden under compute
        f32x4v sfr[2][4];
        compute_S(sfr);
#pragma unroll
        for (int mt = 0; mt < 2; ++mt)
#pragma unroll
            for (int n = 0; n < 4; ++n)
#pragma unroll
                for (int r = 0; r < 4; ++r)
                    lsum[mt][r] += __expf(fmaf(sfr[mt][n][r], 0.125f, -8.0f));
    }

    float rsc[2][4];
#pragma unroll
    for (int mt = 0; mt < 2; ++mt)
#pragma unroll
        for (int r = 0; r < 4; ++r) {
            float v = lsum[mt][r];
            v += __shfl_xor(v, 1);
            v += __shfl_xor(v, 2);
            v += __shfl_xor(v, 4);
            v += __shfl_xor(v, 8);
            rsc[mt][r] = 1.0f / (0.9f * v);   // folds dropout 1/(1-p)
        }

    // ---- pass B: recompute s, exact p, dropout, fp16 cast, PV ----
    f32x4v oacc[2][4];
#pragma unroll
    for (int mt = 0; mt < 2; ++mt)
#pragma unroll
        for (int fn = 0; fn < 4; ++fn)
            oacc[mt][fn] = f32x4v{0.f, 0.f, 0.f, 0.f};

    fetch_k(0); fetch_v(0); fetch_m(0);
    for (int kt = 0; kt < 32; ++kt) {
        __syncthreads();
        commit_k(); commit_v();
        m_l[t] = pm;
        __syncthreads();
        if (kt < 31) { fetch_k(kt + 1); fetch_v(kt + 1); fetch_m(kt + 1); }

        f32x4v sfr[2][4];
        compute_S(sfr);

#pragma unroll
        for (int mt = 0; mt < 2; ++mt)
#pragma unroll
            for (int n = 0; n < 4; ++n)
#pragma unroll
                for (int r = 0; r < 4; ++r) {
                    float e = __expf(fmaf(sfr[mt][n][r], 0.125f, -8.0f));
                    float p = e * rsc[mt][r];
                    int rb = w * 32 + mt * 16 + kg * 4 + r;
                    int cc = n * 16 + lrow;
                    u32 wv = m_l[rb * 2 + (n >> 1)];
                    if (!((wv >> (cc & 31)) & 1u)) p = 0.0f;
                    p_l[w][(mt * 16 + kg * 4 + r) * LDK + cc] = (f16)p;  // RTNE, matches astype(f16)
                }

        // PV: out += P(16f exact) * (Vh + Vl)   (wave-private p_l: no barrier)
#pragma unroll
        for (int ks = 0; ks < 2; ++ks) {
            f16x8 pa0 = *(const f16x8*)&p_l[w][lrow * LDK + ks * 32 + kg * 8];
            f16x8 pa1 = *(const f16x8*)&p_l[w][(16 + lrow) * LDK + ks * 32 + kg * 8];
#pragma unroll
            for (int fn = 0; fn < 4; ++fn) {
                const int voff = (fn * 16 + lrow) * LDK + ks * 32 + kg * 8;
                f16x8 vhf = *(const f16x8*)&vh_l[voff];
                f16x8 vlf = *(const f16x8*)&vl_l[voff];
                oacc[0][fn] = __builtin_amdgcn_mfma_f32_16x16x32_f16(pa0, vhf, oacc[0][fn], 0, 0, 0);
                oacc[0][fn] = __builtin_amdgcn_mfma_f32_16x16x32_f16(pa0, vlf, oacc[0][fn], 0, 0, 0);
                oacc[1][fn] = __builtin_amdgcn_mfma_f32_16x16x32_f16(pa1, vhf, oacc[1][fn], 0, 0, 0);
                oacc[1][fn] = __builtin_amdgcn_mfma_f32_16x16x32_f16(pa1, vlf, oacc[1][fn], 0, 0, 0);
            }
        }
    }

    // epilogue: out [b,h,s,e] fp32
#pragma unroll
    for (int mt = 0; mt < 2; ++mt)
#pragma unroll
        for (int fn = 0; fn < 4; ++fn)
#pragma unroll
            for (int r = 0; r < 4; ++r) {
                int row = qt * 128 + w * 32 + mt * 16 + kg * 4 + r;
                out[((size_t)bh * 2048 + row) * 64 + fn * 16 + lrow] = oacc[mt][fn][r];
            }
}

extern "C" void kernel_launch(void* const* d_in, const int* in_sizes, int n_in,
                              void* d_out, int out_size, void* d_ws, size_t ws_size,
                              hipStream_t stream) {
    (void)in_sizes; (void)n_in; (void)out_size; (void)ws_size;
    const float* query = (const float*)d_in[0];
    const float* key_  = (const float*)d_in[1];
    const float* value = (const float*)d_in[2];
    const float* Wq = (const float*)d_in[3];
    const float* bq = (const float*)d_in[4];
    const float* Wk = (const float*)d_in[5];
    const float* bk = (const float*)d_in[6];
    const float* Wv = (const float*)d_in[7];
    const float* bv = (const float*)d_in[8];

    char* ws = (char*)d_ws;                 // needs 64 MiB
    f16* Qh  = (f16*)(ws);
    f16* Ql  = (f16*)(ws + 8388608);
    f16* Kh  = (f16*)(ws + 16777216);
    f16* Kl  = (f16*)(ws + 25165824);
    f16* Vth = (f16*)(ws + 33554432);
    f16* Vtl = (f16*)(ws + 41943040);
    u32* mask = (u32*)(ws + 50331648);

    proj_kernel<false><<<512, 256, 0, stream>>>(query, Wq, bq, Qh, Ql);
    proj_kernel<false><<<512, 256, 0, stream>>>(key_,  Wk, bk, Kh, Kl);
    proj_kernel<true ><<<512, 256, 0, stream>>>(value, Wv, bv, Vth, Vtl);
    maskgen_kernel<<<262144, 256, 0, stream>>>(mask);
    attn_kernel<<<dim3(16, 32), 256, 0, stream>>>(Qh, Ql, Kh, Kl, Vth, Vtl, mask, (float*)d_out);
}

// Round 5
// 611.100 us; speedup vs baseline: 1.0650x; 1.0650x over previous
//
#include <hip/hip_runtime.h>
#include <hip/hip_fp16.h>

// Problem: B=4, S=2048, H=8, E=64. BH=32 heads total.
// Pipeline: proj_qk (q,k = x@W^T+b, [b,h,s,e] f16 hi+lo),
//           proj_v  (v -> TRANSPOSED [b,h,e,s], LDS-transposed coalesced stores),
//           attn    (two-pass flash; dropout threefry FUSED into pass B,
//                    mask word computed into a REGISTER during compute phase and
//                    committed to LDS inside the barrier window — R3-proven pattern).
// Workspace: Qh 0, Ql 8M, Kh 16M, Kl 24M, Vth 32M, Vtl 40M  (48 MiB)

typedef _Float16 f16;
typedef _Float16 f16x4 __attribute__((ext_vector_type(4)));
typedef _Float16 f16x8 __attribute__((ext_vector_type(8)));
typedef float f32x4v __attribute__((ext_vector_type(4)));
typedef unsigned int u32;
typedef unsigned long long u64;

// ---------------- proj_qk: out[f] = sum_e x[e]*W[f][e] + b[f], [b,h,s,e] ----------------
__global__ __launch_bounds__(256) void proj_qk_kernel(
    const float* __restrict__ X, const float* __restrict__ W,
    const float* __restrict__ bias,
    f16* __restrict__ Oh, f16* __restrict__ Ol)
{
    __shared__ __align__(16) float Wl[64 * 68];
    __shared__ __align__(16) float Xl[128 * 68];
    const int t = threadIdx.x;
    const int tb = blockIdx.x * 128;

    for (int c = t; c < 1024; c += 256) {
        int f = c >> 4, e4 = (c & 15) << 2;
        *(float4*)&Wl[f * 68 + e4] = *(const float4*)(W + f * 64 + e4);
    }
    for (int c = t; c < 2048; c += 256) {
        int tok = c >> 4, e4 = (c & 15) << 2;
        *(float4*)&Xl[tok * 68 + e4] = *(const float4*)(X + (size_t)(tb + tok) * 64 + e4);
    }
    __syncthreads();

    const int tx = t & 15;
    const int ty = t >> 4;
    const int f0 = ty * 4;

    float acc[8][4];
#pragma unroll
    for (int i = 0; i < 8; ++i)
#pragma unroll
        for (int j = 0; j < 4; ++j) acc[i][j] = bias[f0 + j];

    for (int e = 0; e < 64; e += 4) {
        float4 wv[4];
#pragma unroll
        for (int j = 0; j < 4; ++j) wv[j] = *(float4*)&Wl[(f0 + j) * 68 + e];
#pragma unroll
        for (int i = 0; i < 8; ++i) {
            float4 xv = *(float4*)&Xl[(tx + 16 * i) * 68 + e];
#pragma unroll
            for (int j = 0; j < 4; ++j)
                acc[i][j] += xv.x * wv[j].x + xv.y * wv[j].y + xv.z * wv[j].z + xv.w * wv[j].w;
        }
    }

#pragma unroll
    for (int i = 0; i < 8; ++i) {
        int tin = tb + tx + 16 * i;
        int h  = tin & 7;
        int bs = tin >> 3;
        int b  = bs >> 11;
        int s  = bs & 2047;
        size_t o = ((size_t)(b * 8 + h) * 2048 + s) * 64 + f0;
        f16x4 hv, lv;
#pragma unroll
        for (int j = 0; j < 4; ++j) {
            float a = acc[i][j];
            f16 hh = (f16)a;
            hv[j] = hh;
            lv[j] = (f16)(a - (float)hh);
        }
        *(f16x4*)(Oh + o) = hv;
        *(f16x4*)(Ol + o) = lv;
    }
}

// ---------------- proj_v: one (bh, 128-s chunk) per block; store [b,h,e,s] coalesced ----------------
__global__ __launch_bounds__(256) void proj_v_kernel(
    const float* __restrict__ X, const float* __restrict__ W,
    const float* __restrict__ bias,
    f16* __restrict__ Oh, f16* __restrict__ Ol)
{
    __shared__ __align__(16) float Wl[64 * 68];
    __shared__ __align__(16) float Xl[128 * 68];   // reused as Th/Tl after compute
    const int t = threadIdx.x;
    const int sc0 = blockIdx.x * 128;
    const int bh = blockIdx.y, b = bh >> 3, h = bh & 7;

    for (int c = t; c < 1024; c += 256) {
        int f = c >> 4, e4 = (c & 15) << 2;
        *(float4*)&Wl[f * 68 + e4] = *(const float4*)(W + f * 64 + e4);
    }
    for (int c = t; c < 2048; c += 256) {          // tokens of same (b,h): stride 8 in [B,S,H,E]
        int tok = c >> 4, e4 = (c & 15) << 2;
        size_t src = ((size_t)(b * 2048 + sc0 + tok) * 8 + h) * 64 + e4;
        *(float4*)&Xl[tok * 68 + e4] = *(const float4*)(X + src);
    }
    __syncthreads();

    const int tx = t & 15;
    const int ty = t >> 4;
    const int f0 = ty * 4;

    float acc[8][4];
#pragma unroll
    for (int i = 0; i < 8; ++i)
#pragma unroll
        for (int j = 0; j < 4; ++j) acc[i][j] = bias[f0 + j];

    for (int e = 0; e < 64; e += 4) {
        float4 wv[4];
#pragma unroll
        for (int j = 0; j < 4; ++j) wv[j] = *(float4*)&Wl[(f0 + j) * 68 + e];
#pragma unroll
        for (int i = 0; i < 8; ++i) {
            float4 xv = *(float4*)&Xl[(tx + 16 * i) * 68 + e];
#pragma unroll
            for (int j = 0; j < 4; ++j)
                acc[i][j] += xv.x * wv[j].x + xv.y * wv[j].y + xv.z * wv[j].z + xv.w * wv[j].w;
        }
    }
    __syncthreads();                               // done reading Xl -> reuse as transpose tile

    f16* Th = (f16*)Xl;            // [64 f][136 s]  (136*2 B rows, 16B-aligned)
    f16* Tl = Th + 64 * 136;
#pragma unroll
    for (int i = 0; i < 8; ++i) {
        int s = tx + 16 * i;
#pragma unroll
        for (int j = 0; j < 4; ++j) {
            float a = acc[i][j];
            f16 hh = (f16)a;
            Th[(f0 + j) * 136 + s] = hh;
            Tl[(f0 + j) * 136 + s] = (f16)(a - (float)hh);
        }
    }
    __syncthreads();

    for (int c = t; c < 1024; c += 256) {          // 64 e-rows x 128 s, uint4 = 8 f16
        int e = c >> 4, sc = (c & 15) << 3;
        size_t o = ((size_t)bh * 64 + e) * 2048 + sc0 + sc;
        *(uint4*)(Oh + o) = *(uint4*)&Th[e * 136 + sc];
        *(uint4*)(Ol + o) = *(uint4*)&Tl[e * 136 + sc];
    }
}

// ---------------- threefry2x32 (jax partitionable), key (0,42) — macro-inlined ----------------
// per flat i over [B,H,S,S]: (b1,b2)=threefry2x32((0,42),(0,i)); keep <=> (b1^b2) < 0xE6666600
#define QR2(r) \
    a0 += a1; b0 += b1; \
    a1 = __builtin_rotateleft32(a1, r); b1 = __builtin_rotateleft32(b1, r); \
    a1 ^= a0; b1 ^= b0;
#define TF4(p,q,rr,s) QR2(p) QR2(q) QR2(rr) QR2(s)
#define TF_FULL \
    TF4(13,15,26,6)   a0 += 42u;          a1 += 0x1BD11BF1u;  b0 += 42u;          b1 += 0x1BD11BF1u; \
    TF4(17,29,16,24)  a0 += 0x1BD11BF0u;  a1 += 2u;           b0 += 0x1BD11BF0u;  b1 += 2u; \
    TF4(13,15,26,6)                       a1 += 45u;                              b1 += 45u; \
    TF4(17,29,16,24)  a0 += 42u;          a1 += 0x1BD11BF4u;  b0 += 42u;          b1 += 0x1BD11BF4u; \
    TF4(13,15,26,6)   a0 += 0x1BD11BF0u;  a1 += 5u;           b0 += 0x1BD11BF0u;  b1 += 5u;

// one 32-col mask word for (row = qt*128 + (t>>1), cols kt*64 + (t&1)*32 + 0..31) -> REGISTER
#define MASK_WORD(ktArg, dst) do { \
    u32 wm_ = 0u; \
    const u32 eb_ = (((u32)bh * 2048u + (u32)(qt * 128 + (t >> 1))) << 11) \
                  + (u32)(ktArg) * 64u + (u32)(t & 1) * 32u + 42u; \
    _Pragma("unroll 2") \
    for (int j_ = 0; j_ < 16; ++j_) { \
        u32 a0 = 0u, a1 = eb_ + (u32)j_; \
        u32 b0 = 0u, b1 = eb_ + (u32)j_ + 16u; \
        TF_FULL \
        wm_ |= ((a0 ^ a1) < 0xE6666600u) ? (1u << j_) : 0u; \
        wm_ |= ((b0 ^ b1) < 0xE6666600u) ? (1u << (j_ + 16)) : 0u; \
    } \
    (dst) = wm_; \
} while (0)

// ---------------- attention staging macros (no lambdas -> no scratch) ----------------
#define FETCH_K(ktArg) do { \
    _Pragma("unroll") for (int ci = 0; ci < 2; ++ci) { \
        int c_ = t + 256 * ci; int r_ = c_ >> 3, c8_ = (c_ & 7) << 3; \
        size_t g_ = kbase + (size_t)((ktArg) * 64 + r_) * 64 + c8_; \
        pk[ci][0] = *(const uint4*)(Kh + g_); pk[ci][1] = *(const uint4*)(Kl + g_); \
    } } while (0)
#define COMMIT_K() do { \
    _Pragma("unroll") for (int ci = 0; ci < 2; ++ci) { \
        int c_ = t + 256 * ci; int r_ = c_ >> 3, c8_ = (c_ & 7) << 3; \
        *(uint4*)&kh_l[r_ * LDK + c8_] = pk[ci][0]; \
        *(uint4*)&kl_l[r_ * LDK + c8_] = pk[ci][1]; \
    } } while (0)
#define FETCH_V(ktArg) do { \
    _Pragma("unroll") for (int ci = 0; ci < 2; ++ci) { \
        int c_ = t + 256 * ci; int e_ = c_ >> 3, c8_ = (c_ & 7) << 3; \
        size_t g_ = kbase + (size_t)e_ * 2048 + (ktArg) * 64 + c8_; \
        pv[ci][0] = *(const uint4*)(Vth + g_); pv[ci][1] = *(const uint4*)(Vtl + g_); \
    } } while (0)
#define COMMIT_V() do { \
    _Pragma("unroll") for (int ci = 0; ci < 2; ++ci) { \
        int c_ = t + 256 * ci; int e_ = c_ >> 3, c8_ = (c_ & 7) << 3; \
        *(uint4*)&vh_l[e_ * LDK + c8_] = pv[ci][0]; \
        *(uint4*)&vl_l[e_ * LDK + c8_] = pv[ci][1]; \
    } } while (0)

// identical score computation for both passes (bit-identical chain order)
#define COMPUTE_S(S) do { \
    _Pragma("unroll") for (int mt = 0; mt < 2; ++mt) \
        _Pragma("unroll") for (int n = 0; n < 4; ++n) S[mt][n] = f32x4v{0.f,0.f,0.f,0.f}; \
    _Pragma("unroll") for (int n = 0; n < 4; ++n) { \
        _Pragma("unroll") for (int ks = 0; ks < 2; ++ks) { \
            const int off_ = (n * 16 + lrow) * LDK + ks * 32 + kg * 8; \
            f16x8 bhf_ = *(const f16x8*)&kh_l[off_]; \
            f16x8 blf_ = *(const f16x8*)&kl_l[off_]; \
            _Pragma("unroll") for (int mt = 0; mt < 2; ++mt) { \
                S[mt][n] = __builtin_amdgcn_mfma_f32_16x16x32_f16(qh[mt][ks], bhf_, S[mt][n], 0, 0, 0); \
                S[mt][n] = __builtin_amdgcn_mfma_f32_16x16x32_f16(ql[mt][ks], bhf_, S[mt][n], 0, 0, 0); \
                S[mt][n] = __builtin_amdgcn_mfma_f32_16x16x32_f16(qh[mt][ks], blf_, S[mt][n], 0, 0, 0); \
            } \
        } \
    } } while (0)

// grid (16, 32): x = 128-row Q tile, y = bh. 4 waves x 32 rows.
// MFMA 16x16x32 f16. A: A[m=lane&15][k=(lane>>4)*8+j]; B: B[k][n=lane&15];
// C: row=(lane>>4)*4+r, col=lane&15.
__global__ __launch_bounds__(256, 2) void attn_kernel(
    const f16* __restrict__ Qh, const f16* __restrict__ Ql,
    const f16* __restrict__ Kh, const f16* __restrict__ Kl,
    const f16* __restrict__ Vth, const f16* __restrict__ Vtl,
    float* __restrict__ out)
{
    constexpr int LDK = 88;   // f16 stride: 176 B rows (16B aligned)
    __shared__ __align__(16) f16 kh_l[64 * LDK];
    __shared__ __align__(16) f16 kl_l[64 * LDK];
    __shared__ __align__(16) f16 vh_l[64 * LDK];   // [e][s]
    __shared__ __align__(16) f16 vl_l[64 * LDK];
    __shared__ __align__(16) f16 p_l[4][32 * LDK]; // per-wave P tile
    __shared__ u32 m_l[256];                       // 128 q-rows x 2 words (single buffer)

    const int t = threadIdx.x;
    const int w = t >> 6;
    const int lane = t & 63;
    const int lrow = lane & 15;
    const int kg = lane >> 4;
    const int qt = blockIdx.x;
    const int bh = blockIdx.y;

    // persistent Q fragments (hi/lo), 2 m-tiles x 2 k-steps
    f16x8 qh[2][2], ql[2][2];
#pragma unroll
    for (int mt = 0; mt < 2; ++mt) {
        size_t rowg = (size_t)bh * 2048 + qt * 128 + w * 32 + mt * 16 + lrow;
        const f16* ph = Qh + rowg * 64 + kg * 8;
        const f16* pl = Ql + rowg * 64 + kg * 8;
        qh[mt][0] = *(const f16x8*)(ph);
        qh[mt][1] = *(const f16x8*)(ph + 32);
        ql[mt][0] = *(const f16x8*)(pl);
        ql[mt][1] = *(const f16x8*)(pl + 32);
    }

    const size_t kbase = (size_t)bh * 2048 * 64;   // same footprint for K and Vt
    uint4 pk[2][2], pv[2][2];
    u32 pm;

    // ---- pass A: row sums l = sum exp(s - 8) (fixed shift; cancels in e/l) ----
    float lsum[2][4] = {{0.f, 0.f, 0.f, 0.f}, {0.f, 0.f, 0.f, 0.f}};
    FETCH_K(0);
    for (int kt = 0; kt < 32; ++kt) {
        __syncthreads();
        COMMIT_K();
        __syncthreads();
        if (kt < 31) FETCH_K(kt + 1);
        f32x4v sfr[2][4];
        COMPUTE_S(sfr);
#pragma unroll
        for (int mt = 0; mt < 2; ++mt)
#pragma unroll
            for (int n = 0; n < 4; ++n)
#pragma unroll
                for (int r = 0; r < 4; ++r)
                    lsum[mt][r] += __expf(fmaf(sfr[mt][n][r], 0.125f, -8.0f));
    }

    float rsc[2][4];
#pragma unroll
    for (int mt = 0; mt < 2; ++mt)
#pragma unroll
        for (int r = 0; r < 4; ++r) {
            float v = lsum[mt][r];
            v += __shfl_xor(v, 1);
            v += __shfl_xor(v, 2);
            v += __shfl_xor(v, 4);
            v += __shfl_xor(v, 8);
            rsc[mt][r] = 1.0f / (0.9f * v);   // folds dropout 1/(1-p)
        }

    // ---- pass B: recompute s, exact p, fused-threefry dropout, fp16 cast, PV ----
    f32x4v oacc[2][4];
#pragma unroll
    for (int mt = 0; mt < 2; ++mt)
#pragma unroll
        for (int fn = 0; fn < 4; ++fn)
            oacc[mt][fn] = f32x4v{0.f, 0.f, 0.f, 0.f};

    FETCH_K(0); FETCH_V(0);
    MASK_WORD(0, pm);                   // into register; committed inside barrier window

    for (int kt = 0; kt < 32; ++kt) {
        __syncthreads();
        COMMIT_K(); COMMIT_V();
        m_l[t] = pm;                    // LDS write strictly inside the barrier pair
        __syncthreads();
        if (kt < 31) { FETCH_K(kt + 1); FETCH_V(kt + 1); }

        f32x4v sfr[2][4];
        COMPUTE_S(sfr);

        // threefry for NEXT tile into a register — overlaps MFMA drain; no LDS touch
        if (kt < 31) MASK_WORD(kt + 1, pm);

#pragma unroll
        for (int mt = 0; mt < 2; ++mt)
#pragma unroll
            for (int n = 0; n < 4; ++n)
#pragma unroll
                for (int r = 0; r < 4; ++r) {
                    float e = __expf(fmaf(sfr[mt][n][r], 0.125f, -8.0f));
                    float p = e * rsc[mt][r];
                    int rb = w * 32 + mt * 16 + kg * 4 + r;
                    int cc = n * 16 + lrow;
                    u32 wv = m_l[rb * 2 + (n >> 1)];
                    if (!((wv >> (cc & 31)) & 1u)) p = 0.0f;
                    p_l[w][(mt * 16 + kg * 4 + r) * LDK + cc] = (f16)p;  // RTNE = astype(f16)
                }

        // PV: out += P(16f exact) * (Vh + Vl)   (wave-private p_l: no barrier)
#pragma unroll
        for (int ks = 0; ks < 2; ++ks) {
            f16x8 pa0 = *(const f16x8*)&p_l[w][lrow * LDK + ks * 32 + kg * 8];
            f16x8 pa1 = *(const f16x8*)&p_l[w][(16 + lrow) * LDK + ks * 32 + kg * 8];
#pragma unroll
            for (int fn = 0; fn < 4; ++fn) {
                const int voff = (fn * 16 + lrow) * LDK + ks * 32 + kg * 8;
                f16x8 vhf = *(const f16x8*)&vh_l[voff];
                f16x8 vlf = *(const f16x8*)&vl_l[voff];
                oacc[0][fn] = __builtin_amdgcn_mfma_f32_16x16x32_f16(pa0, vhf, oacc[0][fn], 0, 0, 0);
                oacc[0][fn] = __builtin_amdgcn_mfma_f32_16x16x32_f16(pa0, vlf, oacc[0][fn], 0, 0, 0);
                oacc[1][fn] = __builtin_amdgcn_mfma_f32_16x16x32_f16(pa1, vhf, oacc[1][fn], 0, 0, 0);
                oacc[1][fn] = __builtin_amdgcn_mfma_f32_16x16x32_f16(pa1, vlf, oacc[1][fn], 0, 0, 0);
            }
        }
    }

    // epilogue: out [b,h,s,e] fp32
#pragma unroll
    for (int mt = 0; mt < 2; ++mt)
#pragma unroll
        for (int fn = 0; fn < 4; ++fn)
#pragma unroll
            for (int r = 0; r < 4; ++r) {
                int row = qt * 128 + w * 32 + mt * 16 + kg * 4 + r;
                out[((size_t)bh * 2048 + row) * 64 + fn * 16 + lrow] = oacc[mt][fn][r];
            }
}

extern "C" void kernel_launch(void* const* d_in, const int* in_sizes, int n_in,
                              void* d_out, int out_size, void* d_ws, size_t ws_size,
                              hipStream_t stream) {
    (void)in_sizes; (void)n_in; (void)out_size; (void)ws_size;
    const float* query = (const float*)d_in[0];
    const float* key_  = (const float*)d_in[1];
    const float* value = (const float*)d_in[2];
    const float* Wq = (const float*)d_in[3];
    const float* bq = (const float*)d_in[4];
    const float* Wk = (const float*)d_in[5];
    const float* bk = (const float*)d_in[6];
    const float* Wv = (const float*)d_in[7];
    const float* bv = (const float*)d_in[8];

    char* ws = (char*)d_ws;                 // needs 48 MiB
    f16* Qh  = (f16*)(ws);
    f16* Ql  = (f16*)(ws + 8388608);
    f16* Kh  = (f16*)(ws + 16777216);
    f16* Kl  = (f16*)(ws + 25165824);
    f16* Vth = (f16*)(ws + 33554432);
    f16* Vtl = (f16*)(ws + 41943040);

    proj_qk_kernel<<<512, 256, 0, stream>>>(query, Wq, bq, Qh, Ql);
    proj_qk_kernel<<<512, 256, 0, stream>>>(key_,  Wk, bk, Kh, Kl);
    proj_v_kernel<<<dim3(16, 32), 256, 0, stream>>>(value, Wv, bv, Vth, Vtl);
    attn_kernel<<<dim3(16, 32), 256, 0, stream>>>(Qh, Ql, Kh, Kl, Vth, Vtl, (float*)d_out);
}

// Round 6
// 525.500 us; speedup vs baseline: 1.2385x; 1.1629x over previous
//
#include <hip/hip_runtime.h>
#include <hip/hip_fp16.h>

// Problem: B=4, S=2048, H=8, E=64. BH=32 heads total.
// Pipeline: proj_qk (q,k = x@W^T+b, [b,h,s,e] f16 hi+lo),
//           proj_v  (v -> TRANSPOSED [b,h,e,s], LDS-transposed coalesced stores),
//           attn    (two-pass flash; dropout threefry FUSED into pass B compute
//                    phase -> register pm -> committed inside barrier window).
// R6: NO register prefetch of K/V (R5's pk/pv lived across the 1120-inst threefry
//     and spilled -> 392 MB scratch writes). Staging is direct global->LDS in the
//     barrier window with short-lived temps.
// Workspace: Qh 0, Ql 8M, Kh 16M, Kl 24M, Vth 32M, Vtl 40M  (48 MiB)

typedef _Float16 f16;
typedef _Float16 f16x4 __attribute__((ext_vector_type(4)));
typedef _Float16 f16x8 __attribute__((ext_vector_type(8)));
typedef float f32x4v __attribute__((ext_vector_type(4)));
typedef unsigned int u32;

// ---------------- proj_qk: out[f] = sum_e x[e]*W[f][e] + b[f], [b,h,s,e] ----------------
__global__ __launch_bounds__(256) void proj_qk_kernel(
    const float* __restrict__ X, const float* __restrict__ W,
    const float* __restrict__ bias,
    f16* __restrict__ Oh, f16* __restrict__ Ol)
{
    __shared__ __align__(16) float Wl[64 * 68];
    __shared__ __align__(16) float Xl[128 * 68];
    const int t = threadIdx.x;
    const int tb = blockIdx.x * 128;

    for (int c = t; c < 1024; c += 256) {
        int f = c >> 4, e4 = (c & 15) << 2;
        *(float4*)&Wl[f * 68 + e4] = *(const float4*)(W + f * 64 + e4);
    }
    for (int c = t; c < 2048; c += 256) {
        int tok = c >> 4, e4 = (c & 15) << 2;
        *(float4*)&Xl[tok * 68 + e4] = *(const float4*)(X + (size_t)(tb + tok) * 64 + e4);
    }
    __syncthreads();

    const int tx = t & 15;
    const int ty = t >> 4;
    const int f0 = ty * 4;

    float acc[8][4];
#pragma unroll
    for (int i = 0; i < 8; ++i)
#pragma unroll
        for (int j = 0; j < 4; ++j) acc[i][j] = bias[f0 + j];

    for (int e = 0; e < 64; e += 4) {
        float4 wv[4];
#pragma unroll
        for (int j = 0; j < 4; ++j) wv[j] = *(float4*)&Wl[(f0 + j) * 68 + e];
#pragma unroll
        for (int i = 0; i < 8; ++i) {
            float4 xv = *(float4*)&Xl[(tx + 16 * i) * 68 + e];
#pragma unroll
            for (int j = 0; j < 4; ++j)
                acc[i][j] += xv.x * wv[j].x + xv.y * wv[j].y + xv.z * wv[j].z + xv.w * wv[j].w;
        }
    }

#pragma unroll
    for (int i = 0; i < 8; ++i) {
        int tin = tb + tx + 16 * i;
        int h  = tin & 7;
        int bs = tin >> 3;
        int b  = bs >> 11;
        int s  = bs & 2047;
        size_t o = ((size_t)(b * 8 + h) * 2048 + s) * 64 + f0;
        f16x4 hv, lv;
#pragma unroll
        for (int j = 0; j < 4; ++j) {
            float a = acc[i][j];
            f16 hh = (f16)a;
            hv[j] = hh;
            lv[j] = (f16)(a - (float)hh);
        }
        *(f16x4*)(Oh + o) = hv;
        *(f16x4*)(Ol + o) = lv;
    }
}

// ---------------- proj_v: one (bh, 128-s chunk) per block; store [b,h,e,s] coalesced ----------------
__global__ __launch_bounds__(256) void proj_v_kernel(
    const float* __restrict__ X, const float* __restrict__ W,
    const float* __restrict__ bias,
    f16* __restrict__ Oh, f16* __restrict__ Ol)
{
    __shared__ __align__(16) float Wl[64 * 68];
    __shared__ __align__(16) float Xl[128 * 68];   // reused as Th/Tl after compute
    const int t = threadIdx.x;
    const int sc0 = blockIdx.x * 128;
    const int bh = blockIdx.y, b = bh >> 3, h = bh & 7;

    for (int c = t; c < 1024; c += 256) {
        int f = c >> 4, e4 = (c & 15) << 2;
        *(float4*)&Wl[f * 68 + e4] = *(const float4*)(W + f * 64 + e4);
    }
    for (int c = t; c < 2048; c += 256) {          // tokens of same (b,h): stride 8 in [B,S,H,E]
        int tok = c >> 4, e4 = (c & 15) << 2;
        size_t src = ((size_t)(b * 2048 + sc0 + tok) * 8 + h) * 64 + e4;
        *(float4*)&Xl[tok * 68 + e4] = *(const float4*)(X + src);
    }
    __syncthreads();

    const int tx = t & 15;
    const int ty = t >> 4;
    const int f0 = ty * 4;

    float acc[8][4];
#pragma unroll
    for (int i = 0; i < 8; ++i)
#pragma unroll
        for (int j = 0; j < 4; ++j) acc[i][j] = bias[f0 + j];

    for (int e = 0; e < 64; e += 4) {
        float4 wv[4];
#pragma unroll
        for (int j = 0; j < 4; ++j) wv[j] = *(float4*)&Wl[(f0 + j) * 68 + e];
#pragma unroll
        for (int i = 0; i < 8; ++i) {
            float4 xv = *(float4*)&Xl[(tx + 16 * i) * 68 + e];
#pragma unroll
            for (int j = 0; j < 4; ++j)
                acc[i][j] += xv.x * wv[j].x + xv.y * wv[j].y + xv.z * wv[j].z + xv.w * wv[j].w;
        }
    }
    __syncthreads();                               // done reading Xl -> reuse as transpose tile

    f16* Th = (f16*)Xl;            // [64 f][136 s]
    f16* Tl = Th + 64 * 136;
#pragma unroll
    for (int i = 0; i < 8; ++i) {
        int s = tx + 16 * i;
#pragma unroll
        for (int j = 0; j < 4; ++j) {
            float a = acc[i][j];
            f16 hh = (f16)a;
            Th[(f0 + j) * 136 + s] = hh;
            Tl[(f0 + j) * 136 + s] = (f16)(a - (float)hh);
        }
    }
    __syncthreads();

    for (int c = t; c < 1024; c += 256) {          // 64 e-rows x 128 s, uint4 = 8 f16
        int e = c >> 4, sc = (c & 15) << 3;
        size_t o = ((size_t)bh * 64 + e) * 2048 + sc0 + sc;
        *(uint4*)(Oh + o) = *(uint4*)&Th[e * 136 + sc];
        *(uint4*)(Ol + o) = *(uint4*)&Tl[e * 136 + sc];
    }
}

// ---------------- threefry2x32 (jax partitionable), key (0,42) — macro-inlined ----------------
// per flat i over [B,H,S,S]: (b1,b2)=threefry2x32((0,42),(0,i)); keep <=> (b1^b2) < 0xE6666600
#define QR2(r) \
    a0 += a1; b0 += b1; \
    a1 = __builtin_rotateleft32(a1, r); b1 = __builtin_rotateleft32(b1, r); \
    a1 ^= a0; b1 ^= b0;
#define TF4(p,q,rr,s) QR2(p) QR2(q) QR2(rr) QR2(s)
#define TF_FULL \
    TF4(13,15,26,6)   a0 += 42u;          a1 += 0x1BD11BF1u;  b0 += 42u;          b1 += 0x1BD11BF1u; \
    TF4(17,29,16,24)  a0 += 0x1BD11BF0u;  a1 += 2u;           b0 += 0x1BD11BF0u;  b1 += 2u; \
    TF4(13,15,26,6)                       a1 += 45u;                              b1 += 45u; \
    TF4(17,29,16,24)  a0 += 42u;          a1 += 0x1BD11BF4u;  b0 += 42u;          b1 += 0x1BD11BF4u; \
    TF4(13,15,26,6)   a0 += 0x1BD11BF0u;  a1 += 5u;           b0 += 0x1BD11BF0u;  b1 += 5u;

// one 32-col mask word for (row = qt*128 + (t>>1), cols kt*64 + (t&1)*32 + 0..31) -> REGISTER
#define MASK_WORD(ktArg, dst) do { \
    u32 wm_ = 0u; \
    const u32 eb_ = (((u32)bh * 2048u + (u32)(qt * 128 + (t >> 1))) << 11) \
                  + (u32)(ktArg) * 64u + (u32)(t & 1) * 32u + 42u; \
    _Pragma("unroll 2") \
    for (int j_ = 0; j_ < 16; ++j_) { \
        u32 a0 = 0u, a1 = eb_ + (u32)j_; \
        u32 b0 = 0u, b1 = eb_ + (u32)j_ + 16u; \
        TF_FULL \
        wm_ |= ((a0 ^ a1) < 0xE6666600u) ? (1u << j_) : 0u; \
        wm_ |= ((b0 ^ b1) < 0xE6666600u) ? (1u << (j_ + 16)) : 0u; \
    } \
    (dst) = wm_; \
} while (0)

// ---------------- attention staging: direct global->LDS, short-lived temps ----------------
#define STAGE_K(ktArg) do { \
    _Pragma("unroll") for (int ci = 0; ci < 2; ++ci) { \
        int c_ = t + 256 * ci; int r_ = c_ >> 3, c8_ = (c_ & 7) << 3; \
        size_t g_ = kbase + (size_t)((ktArg) * 64 + r_) * 64 + c8_; \
        uint4 h4_ = *(const uint4*)(Kh + g_); \
        uint4 l4_ = *(const uint4*)(Kl + g_); \
        *(uint4*)&kh_l[r_ * LDK + c8_] = h4_; \
        *(uint4*)&kl_l[r_ * LDK + c8_] = l4_; \
    } } while (0)
#define STAGE_V(ktArg) do { \
    _Pragma("unroll") for (int ci = 0; ci < 2; ++ci) { \
        int c_ = t + 256 * ci; int e_ = c_ >> 3, c8_ = (c_ & 7) << 3; \
        size_t g_ = kbase + (size_t)e_ * 2048 + (ktArg) * 64 + c8_; \
        uint4 h4_ = *(const uint4*)(Vth + g_); \
        uint4 l4_ = *(const uint4*)(Vtl + g_); \
        *(uint4*)&vh_l[e_ * LDK + c8_] = h4_; \
        *(uint4*)&vl_l[e_ * LDK + c8_] = l4_; \
    } } while (0)

// identical score computation for both passes (bit-identical chain order)
#define COMPUTE_S(S) do { \
    _Pragma("unroll") for (int mt = 0; mt < 2; ++mt) \
        _Pragma("unroll") for (int n = 0; n < 4; ++n) S[mt][n] = f32x4v{0.f,0.f,0.f,0.f}; \
    _Pragma("unroll") for (int n = 0; n < 4; ++n) { \
        _Pragma("unroll") for (int ks = 0; ks < 2; ++ks) { \
            const int off_ = (n * 16 + lrow) * LDK + ks * 32 + kg * 8; \
            f16x8 bhf_ = *(const f16x8*)&kh_l[off_]; \
            f16x8 blf_ = *(const f16x8*)&kl_l[off_]; \
            _Pragma("unroll") for (int mt = 0; mt < 2; ++mt) { \
                S[mt][n] = __builtin_amdgcn_mfma_f32_16x16x32_f16(qh[mt][ks], bhf_, S[mt][n], 0, 0, 0); \
                S[mt][n] = __builtin_amdgcn_mfma_f32_16x16x32_f16(ql[mt][ks], bhf_, S[mt][n], 0, 0, 0); \
                S[mt][n] = __builtin_amdgcn_mfma_f32_16x16x32_f16(qh[mt][ks], blf_, S[mt][n], 0, 0, 0); \
            } \
        } \
    } } while (0)

// grid (16, 32): x = 128-row Q tile, y = bh. 4 waves x 32 rows.
// MFMA 16x16x32 f16. A: A[m=lane&15][k=(lane>>4)*8+j]; B: B[k][n=lane&15];
// C: row=(lane>>4)*4+r, col=lane&15.
__global__ __launch_bounds__(256, 2) void attn_kernel(
    const f16* __restrict__ Qh, const f16* __restrict__ Ql,
    const f16* __restrict__ Kh, const f16* __restrict__ Kl,
    const f16* __restrict__ Vth, const f16* __restrict__ Vtl,
    float* __restrict__ out)
{
    constexpr int LDK = 88;   // f16 stride: 176 B rows (16B aligned)
    __shared__ __align__(16) f16 kh_l[64 * LDK];
    __shared__ __align__(16) f16 kl_l[64 * LDK];
    __shared__ __align__(16) f16 vh_l[64 * LDK];   // [e][s]
    __shared__ __align__(16) f16 vl_l[64 * LDK];
    __shared__ __align__(16) f16 p_l[4][32 * LDK]; // per-wave P tile
    __shared__ u32 m_l[256];                       // word t: row qt*128+(t>>1), half (t&1)

    const int t = threadIdx.x;
    const int w = t >> 6;
    const int lane = t & 63;
    const int lrow = lane & 15;
    const int kg = lane >> 4;
    const int qt = blockIdx.x;
    const int bh = blockIdx.y;

    // persistent Q fragments (hi/lo), 2 m-tiles x 2 k-steps
    f16x8 qh[2][2], ql[2][2];
#pragma unroll
    for (int mt = 0; mt < 2; ++mt) {
        size_t rowg = (size_t)bh * 2048 + qt * 128 + w * 32 + mt * 16 + lrow;
        const f16* ph = Qh + rowg * 64 + kg * 8;
        const f16* pl = Ql + rowg * 64 + kg * 8;
        qh[mt][0] = *(const f16x8*)(ph);
        qh[mt][1] = *(const f16x8*)(ph + 32);
        ql[mt][0] = *(const f16x8*)(pl);
        ql[mt][1] = *(const f16x8*)(pl + 32);
    }

    const size_t kbase = (size_t)bh * 2048 * 64;   // same footprint for K and Vt
    u32 pm;

    // ---- pass A: row sums l = sum exp(s - 8) (fixed shift; cancels in e/l) ----
    float lsum[2][4] = {{0.f, 0.f, 0.f, 0.f}, {0.f, 0.f, 0.f, 0.f}};
    for (int kt = 0; kt < 32; ++kt) {
        __syncthreads();
        STAGE_K(kt);
        __syncthreads();
        f32x4v sfr[2][4];
        COMPUTE_S(sfr);
#pragma unroll
        for (int mt = 0; mt < 2; ++mt)
#pragma unroll
            for (int n = 0; n < 4; ++n)
#pragma unroll
                for (int r = 0; r < 4; ++r)
                    lsum[mt][r] += __expf(fmaf(sfr[mt][n][r], 0.125f, -8.0f));
    }

    float rsc[2][4];
#pragma unroll
    for (int mt = 0; mt < 2; ++mt)
#pragma unroll
        for (int r = 0; r < 4; ++r) {
            float v = lsum[mt][r];
            v += __shfl_xor(v, 1);
            v += __shfl_xor(v, 2);
            v += __shfl_xor(v, 4);
            v += __shfl_xor(v, 8);
            rsc[mt][r] = 1.0f / (0.9f * v);   // folds dropout 1/(1-p)
        }

    // ---- pass B: recompute s, exact p, fused-threefry dropout, fp16 cast, PV ----
    f32x4v oacc[2][4];
#pragma unroll
    for (int mt = 0; mt < 2; ++mt)
#pragma unroll
        for (int fn = 0; fn < 4; ++fn)
            oacc[mt][fn] = f32x4v{0.f, 0.f, 0.f, 0.f};

    MASK_WORD(0, pm);                   // into register; committed inside barrier window

    for (int kt = 0; kt < 32; ++kt) {
        __syncthreads();
        STAGE_K(kt); STAGE_V(kt);
        m_l[t] = pm;                    // LDS write strictly inside the barrier pair
        __syncthreads();

        f32x4v sfr[2][4];
        COMPUTE_S(sfr);

        // threefry for NEXT tile into a register — overlaps MFMA drain; no LDS touch
        if (kt < 31) MASK_WORD(kt + 1, pm);

#pragma unroll
        for (int mt = 0; mt < 2; ++mt)
#pragma unroll
            for (int n = 0; n < 4; ++n)
#pragma unroll
                for (int r = 0; r < 4; ++r) {
                    float e = __expf(fmaf(sfr[mt][n][r], 0.125f, -8.0f));
                    float p = e * rsc[mt][r];
                    int rb = w * 32 + mt * 16 + kg * 4 + r;
                    int cc = n * 16 + lrow;
                    u32 wv = m_l[rb * 2 + (n >> 1)];
                    if (!((wv >> (cc & 31)) & 1u)) p = 0.0f;
                    p_l[w][(mt * 16 + kg * 4 + r) * LDK + cc] = (f16)p;  // RTNE = astype(f16)
                }

        // PV: out += P(16f exact) * (Vh + Vl)   (wave-private p_l: no barrier)
#pragma unroll
        for (int ks = 0; ks < 2; ++ks) {
            f16x8 pa0 = *(const f16x8*)&p_l[w][lrow * LDK + ks * 32 + kg * 8];
            f16x8 pa1 = *(const f16x8*)&p_l[w][(16 + lrow) * LDK + ks * 32 + kg * 8];
#pragma unroll
            for (int fn = 0; fn < 4; ++fn) {
                const int voff = (fn * 16 + lrow) * LDK + ks * 32 + kg * 8;
                f16x8 vhf = *(const f16x8*)&vh_l[voff];
                f16x8 vlf = *(const f16x8*)&vl_l[voff];
                oacc[0][fn] = __builtin_amdgcn_mfma_f32_16x16x32_f16(pa0, vhf, oacc[0][fn], 0, 0, 0);
                oacc[0][fn] = __builtin_amdgcn_mfma_f32_16x16x32_f16(pa0, vlf, oacc[0][fn], 0, 0, 0);
                oacc[1][fn] = __builtin_amdgcn_mfma_f32_16x16x32_f16(pa1, vhf, oacc[1][fn], 0, 0, 0);
                oacc[1][fn] = __builtin_amdgcn_mfma_f32_16x16x32_f16(pa1, vlf, oacc[1][fn], 0, 0, 0);
            }
        }
    }

    // epilogue: out [b,h,s,e] fp32
#pragma unroll
    for (int mt = 0; mt < 2; ++mt)
#pragma unroll
        for (int fn = 0; fn < 4; ++fn)
#pragma unroll
            for (int r = 0; r < 4; ++r) {
                int row = qt * 128 + w * 32 + mt * 16 + kg * 4 + r;
                out[((size_t)bh * 2048 + row) * 64 + fn * 16 + lrow] = oacc[mt][fn][r];
            }
}

extern "C" void kernel_launch(void* const* d_in, const int* in_sizes, int n_in,
                              void* d_out, int out_size, void* d_ws, size_t ws_size,
                              hipStream_t stream) {
    (void)in_sizes; (void)n_in; (void)out_size; (void)ws_size;
    const float* query = (const float*)d_in[0];
    const float* key_  = (const float*)d_in[1];
    const float* value = (const float*)d_in[2];
    const float* Wq = (const float*)d_in[3];
    const float* bq = (const float*)d_in[4];
    const float* Wk = (const float*)d_in[5];
    const float* bk = (const float*)d_in[6];
    const float* Wv = (const float*)d_in[7];
    const float* bv = (const float*)d_in[8];

    char* ws = (char*)d_ws;                 // needs 48 MiB
    f16* Qh  = (f16*)(ws);
    f16* Ql  = (f16*)(ws + 8388608);
    f16* Kh  = (f16*)(ws + 16777216);
    f16* Kl  = (f16*)(ws + 25165824);
    f16* Vth = (f16*)(ws + 33554432);
    f16* Vtl = (f16*)(ws + 41943040);

    proj_qk_kernel<<<512, 256, 0, stream>>>(query, Wq, bq, Qh, Ql);
    proj_qk_kernel<<<512, 256, 0, stream>>>(key_,  Wk, bk, Kh, Kl);
    proj_v_kernel<<<dim3(16, 32), 256, 0, stream>>>(value, Wv, bv, Vth, Vtl);
    attn_kernel<<<dim3(16, 32), 256, 0, stream>>>(Qh, Ql, Kh, Kl, Vth, Vtl, (float*)d_out);
}

// Round 7
// 498.704 us; speedup vs baseline: 1.3051x; 1.0537x over previous
//
#include <hip/hip_runtime.h>
#include <hip/hip_fp16.h>

// Problem: B=4, S=2048, H=8, E=64. BH=32 heads total.
// R7: attn uses 512-thread blocks (8 waves x 16-row m-tile) -> 4 waves/SIMD
//     for overlap; per-thread work halved (threefry 16 bits/thread via u16
//     half-words). Same total work, same bit-exact math chain as R6.
// Workspace: Qh 0, Ql 8M, Kh 16M, Kl 24M, Vth 32M, Vtl 40M  (48 MiB)

typedef _Float16 f16;
typedef _Float16 f16x4 __attribute__((ext_vector_type(4)));
typedef _Float16 f16x8 __attribute__((ext_vector_type(8)));
typedef float f32x4v __attribute__((ext_vector_type(4)));
typedef unsigned int u32;
typedef unsigned short u16;

// ---------------- proj_qk: out[f] = sum_e x[e]*W[f][e] + b[f], [b,h,s,e] ----------------
__global__ __launch_bounds__(256) void proj_qk_kernel(
    const float* __restrict__ X, const float* __restrict__ W,
    const float* __restrict__ bias,
    f16* __restrict__ Oh, f16* __restrict__ Ol)
{
    __shared__ __align__(16) float Wl[64 * 68];
    __shared__ __align__(16) float Xl[128 * 68];
    const int t = threadIdx.x;
    const int tb = blockIdx.x * 128;

    for (int c = t; c < 1024; c += 256) {
        int f = c >> 4, e4 = (c & 15) << 2;
        *(float4*)&Wl[f * 68 + e4] = *(const float4*)(W + f * 64 + e4);
    }
    for (int c = t; c < 2048; c += 256) {
        int tok = c >> 4, e4 = (c & 15) << 2;
        *(float4*)&Xl[tok * 68 + e4] = *(const float4*)(X + (size_t)(tb + tok) * 64 + e4);
    }
    __syncthreads();

    const int tx = t & 15;
    const int ty = t >> 4;
    const int f0 = ty * 4;

    float acc[8][4];
#pragma unroll
    for (int i = 0; i < 8; ++i)
#pragma unroll
        for (int j = 0; j < 4; ++j) acc[i][j] = bias[f0 + j];

    for (int e = 0; e < 64; e += 4) {
        float4 wv[4];
#pragma unroll
        for (int j = 0; j < 4; ++j) wv[j] = *(float4*)&Wl[(f0 + j) * 68 + e];
#pragma unroll
        for (int i = 0; i < 8; ++i) {
            float4 xv = *(float4*)&Xl[(tx + 16 * i) * 68 + e];
#pragma unroll
            for (int j = 0; j < 4; ++j)
                acc[i][j] += xv.x * wv[j].x + xv.y * wv[j].y + xv.z * wv[j].z + xv.w * wv[j].w;
        }
    }

#pragma unroll
    for (int i = 0; i < 8; ++i) {
        int tin = tb + tx + 16 * i;
        int h  = tin & 7;
        int bs = tin >> 3;
        int b  = bs >> 11;
        int s  = bs & 2047;
        size_t o = ((size_t)(b * 8 + h) * 2048 + s) * 64 + f0;
        f16x4 hv, lv;
#pragma unroll
        for (int j = 0; j < 4; ++j) {
            float a = acc[i][j];
            f16 hh = (f16)a;
            hv[j] = hh;
            lv[j] = (f16)(a - (float)hh);
        }
        *(f16x4*)(Oh + o) = hv;
        *(f16x4*)(Ol + o) = lv;
    }
}

// ---------------- proj_v: one (bh, 128-s chunk) per block; store [b,h,e,s] coalesced ----------------
__global__ __launch_bounds__(256) void proj_v_kernel(
    const float* __restrict__ X, const float* __restrict__ W,
    const float* __restrict__ bias,
    f16* __restrict__ Oh, f16* __restrict__ Ol)
{
    __shared__ __align__(16) float Wl[64 * 68];
    __shared__ __align__(16) float Xl[128 * 68];   // reused as Th/Tl after compute
    const int t = threadIdx.x;
    const int sc0 = blockIdx.x * 128;
    const int bh = blockIdx.y, b = bh >> 3, h = bh & 7;

    for (int c = t; c < 1024; c += 256) {
        int f = c >> 4, e4 = (c & 15) << 2;
        *(float4*)&Wl[f * 68 + e4] = *(const float4*)(W + f * 64 + e4);
    }
    for (int c = t; c < 2048; c += 256) {          // tokens of same (b,h): stride 8 in [B,S,H,E]
        int tok = c >> 4, e4 = (c & 15) << 2;
        size_t src = ((size_t)(b * 2048 + sc0 + tok) * 8 + h) * 64 + e4;
        *(float4*)&Xl[tok * 68 + e4] = *(const float4*)(X + src);
    }
    __syncthreads();

    const int tx = t & 15;
    const int ty = t >> 4;
    const int f0 = ty * 4;

    float acc[8][4];
#pragma unroll
    for (int i = 0; i < 8; ++i)
#pragma unroll
        for (int j = 0; j < 4; ++j) acc[i][j] = bias[f0 + j];

    for (int e = 0; e < 64; e += 4) {
        float4 wv[4];
#pragma unroll
        for (int j = 0; j < 4; ++j) wv[j] = *(float4*)&Wl[(f0 + j) * 68 + e];
#pragma unroll
        for (int i = 0; i < 8; ++i) {
            float4 xv = *(float4*)&Xl[(tx + 16 * i) * 68 + e];
#pragma unroll
            for (int j = 0; j < 4; ++j)
                acc[i][j] += xv.x * wv[j].x + xv.y * wv[j].y + xv.z * wv[j].z + xv.w * wv[j].w;
        }
    }
    __syncthreads();                               // done reading Xl -> reuse as transpose tile

    f16* Th = (f16*)Xl;            // [64 f][136 s]
    f16* Tl = Th + 64 * 136;
#pragma unroll
    for (int i = 0; i < 8; ++i) {
        int s = tx + 16 * i;
#pragma unroll
        for (int j = 0; j < 4; ++j) {
            float a = acc[i][j];
            f16 hh = (f16)a;
            Th[(f0 + j) * 136 + s] = hh;
            Tl[(f0 + j) * 136 + s] = (f16)(a - (float)hh);
        }
    }
    __syncthreads();

    for (int c = t; c < 1024; c += 256) {          // 64 e-rows x 128 s, uint4 = 8 f16
        int e = c >> 4, sc = (c & 15) << 3;
        size_t o = ((size_t)bh * 64 + e) * 2048 + sc0 + sc;
        *(uint4*)(Oh + o) = *(uint4*)&Th[e * 136 + sc];
        *(uint4*)(Ol + o) = *(uint4*)&Tl[e * 136 + sc];
    }
}

// ---------------- threefry2x32 (jax partitionable), key (0,42) — macro-inlined ----------------
// per flat i over [B,H,S,S]: (b1,b2)=threefry2x32((0,42),(0,i)); keep <=> (b1^b2) < 0xE6666600
#define QR2(r) \
    a0 += a1; b0 += b1; \
    a1 = __builtin_rotateleft32(a1, r); b1 = __builtin_rotateleft32(b1, r); \
    a1 ^= a0; b1 ^= b0;
#define TF4(p,q,rr,s) QR2(p) QR2(q) QR2(rr) QR2(s)
#define TF_FULL \
    TF4(13,15,26,6)   a0 += 42u;          a1 += 0x1BD11BF1u;  b0 += 42u;          b1 += 0x1BD11BF1u; \
    TF4(17,29,16,24)  a0 += 0x1BD11BF0u;  a1 += 2u;           b0 += 0x1BD11BF0u;  b1 += 2u; \
    TF4(13,15,26,6)                       a1 += 45u;                              b1 += 45u; \
    TF4(17,29,16,24)  a0 += 42u;          a1 += 0x1BD11BF4u;  b0 += 42u;          b1 += 0x1BD11BF4u; \
    TF4(13,15,26,6)   a0 += 0x1BD11BF0u;  a1 += 5u;           b0 += 0x1BD11BF0u;  b1 += 5u;

// 16 mask bits for (row = qt*128 + (t>>2), cols kt*64 + (t&3)*16 + 0..15) -> REGISTER
#define MASK_HALF(ktArg, dst) do { \
    u32 wm_ = 0u; \
    const u32 eb_ = (((u32)bh * 2048u + (u32)(qt * 128 + (t >> 2))) << 11) \
                  + (u32)(ktArg) * 64u + (u32)(t & 3) * 16u + 42u; \
    _Pragma("unroll") \
    for (int j_ = 0; j_ < 8; ++j_) { \
        u32 a0 = 0u, a1 = eb_ + (u32)j_; \
        u32 b0 = 0u, b1 = eb_ + (u32)j_ + 8u; \
        TF_FULL \
        wm_ |= ((a0 ^ a1) < 0xE6666600u) ? (1u << j_) : 0u; \
        wm_ |= ((b0 ^ b1) < 0xE6666600u) ? (1u << (j_ + 8)) : 0u; \
    } \
    (dst) = wm_; \
} while (0)

// ---------------- attention staging: 512 threads cover a 64x64 f16 tile in one shot ----------------
#define STAGE_K(ktArg) do { \
    int r_ = t >> 3, c8_ = (t & 7) << 3; \
    size_t g_ = kbase + (size_t)((ktArg) * 64 + r_) * 64 + c8_; \
    uint4 h4_ = *(const uint4*)(Kh + g_); \
    uint4 l4_ = *(const uint4*)(Kl + g_); \
    *(uint4*)&kh_l[r_ * LDK + c8_] = h4_; \
    *(uint4*)&kl_l[r_ * LDK + c8_] = l4_; \
} while (0)
#define STAGE_V(ktArg) do { \
    int e_ = t >> 3, c8_ = (t & 7) << 3; \
    size_t g_ = kbase + (size_t)e_ * 2048 + (ktArg) * 64 + c8_; \
    uint4 h4_ = *(const uint4*)(Vth + g_); \
    uint4 l4_ = *(const uint4*)(Vtl + g_); \
    *(uint4*)&vh_l[e_ * LDK + c8_] = h4_; \
    *(uint4*)&vl_l[e_ * LDK + c8_] = l4_; \
} while (0)

// identical score computation for both passes (bit-identical chain order per element)
#define COMPUTE_S(S) do { \
    _Pragma("unroll") for (int n = 0; n < 4; ++n) S[n] = f32x4v{0.f,0.f,0.f,0.f}; \
    _Pragma("unroll") for (int n = 0; n < 4; ++n) { \
        _Pragma("unroll") for (int ks = 0; ks < 2; ++ks) { \
            const int off_ = (n * 16 + lrow) * LDK + ks * 32 + kg * 8; \
            f16x8 bhf_ = *(const f16x8*)&kh_l[off_]; \
            f16x8 blf_ = *(const f16x8*)&kl_l[off_]; \
            S[n] = __builtin_amdgcn_mfma_f32_16x16x32_f16(qh[ks], bhf_, S[n], 0, 0, 0); \
            S[n] = __builtin_amdgcn_mfma_f32_16x16x32_f16(ql[ks], bhf_, S[n], 0, 0, 0); \
            S[n] = __builtin_amdgcn_mfma_f32_16x16x32_f16(qh[ks], blf_, S[n], 0, 0, 0); \
        } \
    } } while (0)

// grid (16, 32): x = 128-row Q tile, y = bh. 8 waves x 16 rows.
// MFMA 16x16x32 f16. A: A[m=lane&15][k=(lane>>4)*8+j]; B: B[k][n=lane&15];
// C: row=(lane>>4)*4+r, col=lane&15.
__global__ __launch_bounds__(512, 4) void attn_kernel(
    const f16* __restrict__ Qh, const f16* __restrict__ Ql,
    const f16* __restrict__ Kh, const f16* __restrict__ Kl,
    const f16* __restrict__ Vth, const f16* __restrict__ Vtl,
    float* __restrict__ out)
{
    constexpr int LDK = 88;   // f16 stride: 176 B rows (16B aligned)
    __shared__ __align__(16) f16 kh_l[64 * LDK];
    __shared__ __align__(16) f16 kl_l[64 * LDK];
    __shared__ __align__(16) f16 vh_l[64 * LDK];   // [e][s]
    __shared__ __align__(16) f16 vl_l[64 * LDK];
    __shared__ __align__(16) f16 p_l[8][16 * LDK]; // per-wave P tile (16 rows)
    __shared__ u32 m_l[256];                       // word r*2+h: row qt*128+r, cols h*32..
    u16* m_l16 = (u16*)m_l;                        // half-word t: row t>>2, cols (t&3)*16

    const int t = threadIdx.x;
    const int w = t >> 6;
    const int lane = t & 63;
    const int lrow = lane & 15;
    const int kg = lane >> 4;
    const int qt = blockIdx.x;
    const int bh = blockIdx.y;

    // persistent Q fragments (hi/lo), one 16-row m-tile per wave, 2 k-steps
    f16x8 qh[2], ql[2];
    {
        size_t rowg = (size_t)bh * 2048 + qt * 128 + w * 16 + lrow;
        const f16* ph = Qh + rowg * 64 + kg * 8;
        const f16* pl = Ql + rowg * 64 + kg * 8;
        qh[0] = *(const f16x8*)(ph);
        qh[1] = *(const f16x8*)(ph + 32);
        ql[0] = *(const f16x8*)(pl);
        ql[1] = *(const f16x8*)(pl + 32);
    }

    const size_t kbase = (size_t)bh * 2048 * 64;   // same footprint for K and Vt
    u32 pm;

    // ---- pass A: row sums l = sum exp(s - 8) (fixed shift; cancels in e/l) ----
    float lsum[4] = {0.f, 0.f, 0.f, 0.f};
    for (int kt = 0; kt < 32; ++kt) {
        __syncthreads();
        STAGE_K(kt);
        __syncthreads();
        f32x4v sfr[4];
        COMPUTE_S(sfr);
#pragma unroll
        for (int n = 0; n < 4; ++n)
#pragma unroll
            for (int r = 0; r < 4; ++r)
                lsum[r] += __expf(fmaf(sfr[n][r], 0.125f, -8.0f));
    }

    float rsc[4];
#pragma unroll
    for (int r = 0; r < 4; ++r) {
        float v = lsum[r];
        v += __shfl_xor(v, 1);
        v += __shfl_xor(v, 2);
        v += __shfl_xor(v, 4);
        v += __shfl_xor(v, 8);
        rsc[r] = 1.0f / (0.9f * v);   // folds dropout 1/(1-p)
    }

    // ---- pass B: recompute s, exact p, fused-threefry dropout, fp16 cast, PV ----
    f32x4v oacc[4];
#pragma unroll
    for (int fn = 0; fn < 4; ++fn) oacc[fn] = f32x4v{0.f, 0.f, 0.f, 0.f};

    MASK_HALF(0, pm);                   // into register; committed inside barrier window

    for (int kt = 0; kt < 32; ++kt) {
        __syncthreads();
        STAGE_K(kt); STAGE_V(kt);
        m_l16[t] = (u16)pm;             // LDS write strictly inside the barrier pair
        __syncthreads();

        f32x4v sfr[4];
        COMPUTE_S(sfr);

        // threefry for NEXT tile into a register — overlaps MFMA drain; no LDS touch
        if (kt < 31) MASK_HALF(kt + 1, pm);

#pragma unroll
        for (int n = 0; n < 4; ++n)
#pragma unroll
            for (int r = 0; r < 4; ++r) {
                float e = __expf(fmaf(sfr[n][r], 0.125f, -8.0f));
                float p = e * rsc[r];
                int rb = w * 16 + kg * 4 + r;      // row within 128-row block
                int cc = n * 16 + lrow;
                u32 wv = m_l[rb * 2 + (n >> 1)];
                if (!((wv >> (cc & 31)) & 1u)) p = 0.0f;
                p_l[w][(kg * 4 + r) * LDK + cc] = (f16)p;  // RTNE = astype(f16)
            }

        // PV: out += P(16f exact) * (Vh + Vl)   (wave-private p_l: no barrier)
#pragma unroll
        for (int ks = 0; ks < 2; ++ks) {
            f16x8 pa0 = *(const f16x8*)&p_l[w][lrow * LDK + ks * 32 + kg * 8];
#pragma unroll
            for (int fn = 0; fn < 4; ++fn) {
                const int voff = (fn * 16 + lrow) * LDK + ks * 32 + kg * 8;
                f16x8 vhf = *(const f16x8*)&vh_l[voff];
                f16x8 vlf = *(const f16x8*)&vl_l[voff];
                oacc[fn] = __builtin_amdgcn_mfma_f32_16x16x32_f16(pa0, vhf, oacc[fn], 0, 0, 0);
                oacc[fn] = __builtin_amdgcn_mfma_f32_16x16x32_f16(pa0, vlf, oacc[fn], 0, 0, 0);
            }
        }
    }

    // epilogue: out [b,h,s,e] fp32
#pragma unroll
    for (int fn = 0; fn < 4; ++fn)
#pragma unroll
        for (int r = 0; r < 4; ++r) {
            int row = qt * 128 + w * 16 + kg * 4 + r;
            out[((size_t)bh * 2048 + row) * 64 + fn * 16 + lrow] = oacc[fn][r];
        }
}

extern "C" void kernel_launch(void* const* d_in, const int* in_sizes, int n_in,
                              void* d_out, int out_size, void* d_ws, size_t ws_size,
                              hipStream_t stream) {
    (void)in_sizes; (void)n_in; (void)out_size; (void)ws_size;
    const float* query = (const float*)d_in[0];
    const float* key_  = (const float*)d_in[1];
    const float* value = (const float*)d_in[2];
    const float* Wq = (const float*)d_in[3];
    const float* bq = (const float*)d_in[4];
    const float* Wk = (const float*)d_in[5];
    const float* bk = (const float*)d_in[6];
    const float* Wv = (const float*)d_in[7];
    const float* bv = (const float*)d_in[8];

    char* ws = (char*)d_ws;                 // needs 48 MiB
    f16* Qh  = (f16*)(ws);
    f16* Ql  = (f16*)(ws + 8388608);
    f16* Kh  = (f16*)(ws + 16777216);
    f16* Kl  = (f16*)(ws + 25165824);
    f16* Vth = (f16*)(ws + 33554432);
    f16* Vtl = (f16*)(ws + 41943040);

    proj_qk_kernel<<<512, 256, 0, stream>>>(query, Wq, bq, Qh, Ql);
    proj_qk_kernel<<<512, 256, 0, stream>>>(key_,  Wk, bk, Kh, Kl);
    proj_v_kernel<<<dim3(16, 32), 256, 0, stream>>>(value, Wv, bv, Vth, Vtl);
    attn_kernel<<<dim3(16, 32), 512, 0, stream>>>(Qh, Ql, Kh, Kl, Vth, Vtl, (float*)d_out);
}

// Round 8
// 477.492 us; speedup vs baseline: 1.3630x; 1.0444x over previous
//
#include <hip/hip_runtime.h>
#include <hip/hip_fp16.h>

// Problem: B=4, S=2048, H=8, E=64. BH=32 heads total.
// R8: attn restructured — 1024-thread blocks (16 waves x 16 rows = 256 Q-rows,
//     grid 8x32 = 1 block/CU), double-buffered K/V LDS, ONE barrier per kt
//     (loads issued at loop top, committed after compute), dropout mask fully
//     per-thread (each thread threefrys exactly its own 16 bits; no m_l LDS).
// Workspace: Qh 0, Ql 8M, Kh 16M, Kl 24M, Vth 32M, Vtl 40M  (48 MiB)

typedef _Float16 f16;
typedef _Float16 f16x4 __attribute__((ext_vector_type(4)));
typedef _Float16 f16x8 __attribute__((ext_vector_type(8)));
typedef float f32x4v __attribute__((ext_vector_type(4)));
typedef unsigned int u32;
typedef unsigned short u16;

// ---------------- proj_qk: out[f] = sum_e x[e]*W[f][e] + b[f], [b,h,s,e] ----------------
__global__ __launch_bounds__(256) void proj_qk_kernel(
    const float* __restrict__ X, const float* __restrict__ W,
    const float* __restrict__ bias,
    f16* __restrict__ Oh, f16* __restrict__ Ol)
{
    __shared__ __align__(16) float Wl[64 * 68];
    __shared__ __align__(16) float Xl[128 * 68];
    const int t = threadIdx.x;
    const int tb = blockIdx.x * 128;

    for (int c = t; c < 1024; c += 256) {
        int f = c >> 4, e4 = (c & 15) << 2;
        *(float4*)&Wl[f * 68 + e4] = *(const float4*)(W + f * 64 + e4);
    }
    for (int c = t; c < 2048; c += 256) {
        int tok = c >> 4, e4 = (c & 15) << 2;
        *(float4*)&Xl[tok * 68 + e4] = *(const float4*)(X + (size_t)(tb + tok) * 64 + e4);
    }
    __syncthreads();

    const int tx = t & 15;
    const int ty = t >> 4;
    const int f0 = ty * 4;

    float acc[8][4];
#pragma unroll
    for (int i = 0; i < 8; ++i)
#pragma unroll
        for (int j = 0; j < 4; ++j) acc[i][j] = bias[f0 + j];

    for (int e = 0; e < 64; e += 4) {
        float4 wv[4];
#pragma unroll
        for (int j = 0; j < 4; ++j) wv[j] = *(float4*)&Wl[(f0 + j) * 68 + e];
#pragma unroll
        for (int i = 0; i < 8; ++i) {
            float4 xv = *(float4*)&Xl[(tx + 16 * i) * 68 + e];
#pragma unroll
            for (int j = 0; j < 4; ++j)
                acc[i][j] += xv.x * wv[j].x + xv.y * wv[j].y + xv.z * wv[j].z + xv.w * wv[j].w;
        }
    }

#pragma unroll
    for (int i = 0; i < 8; ++i) {
        int tin = tb + tx + 16 * i;
        int h  = tin & 7;
        int bs = tin >> 3;
        int b  = bs >> 11;
        int s  = bs & 2047;
        size_t o = ((size_t)(b * 8 + h) * 2048 + s) * 64 + f0;
        f16x4 hv, lv;
#pragma unroll
        for (int j = 0; j < 4; ++j) {
            float a = acc[i][j];
            f16 hh = (f16)a;
            hv[j] = hh;
            lv[j] = (f16)(a - (float)hh);
        }
        *(f16x4*)(Oh + o) = hv;
        *(f16x4*)(Ol + o) = lv;
    }
}

// ---------------- proj_v: one (bh, 128-s chunk) per block; store [b,h,e,s] coalesced ----------------
__global__ __launch_bounds__(256) void proj_v_kernel(
    const float* __restrict__ X, const float* __restrict__ W,
    const float* __restrict__ bias,
    f16* __restrict__ Oh, f16* __restrict__ Ol)
{
    __shared__ __align__(16) float Wl[64 * 68];
    __shared__ __align__(16) float Xl[128 * 68];   // reused as Th/Tl after compute
    const int t = threadIdx.x;
    const int sc0 = blockIdx.x * 128;
    const int bh = blockIdx.y, b = bh >> 3, h = bh & 7;

    for (int c = t; c < 1024; c += 256) {
        int f = c >> 4, e4 = (c & 15) << 2;
        *(float4*)&Wl[f * 68 + e4] = *(const float4*)(W + f * 64 + e4);
    }
    for (int c = t; c < 2048; c += 256) {          // tokens of same (b,h): stride 8 in [B,S,H,E]
        int tok = c >> 4, e4 = (c & 15) << 2;
        size_t src = ((size_t)(b * 2048 + sc0 + tok) * 8 + h) * 64 + e4;
        *(float4*)&Xl[tok * 68 + e4] = *(const float4*)(X + src);
    }
    __syncthreads();

    const int tx = t & 15;
    const int ty = t >> 4;
    const int f0 = ty * 4;

    float acc[8][4];
#pragma unroll
    for (int i = 0; i < 8; ++i)
#pragma unroll
        for (int j = 0; j < 4; ++j) acc[i][j] = bias[f0 + j];

    for (int e = 0; e < 64; e += 4) {
        float4 wv[4];
#pragma unroll
        for (int j = 0; j < 4; ++j) wv[j] = *(float4*)&Wl[(f0 + j) * 68 + e];
#pragma unroll
        for (int i = 0; i < 8; ++i) {
            float4 xv = *(float4*)&Xl[(tx + 16 * i) * 68 + e];
#pragma unroll
            for (int j = 0; j < 4; ++j)
                acc[i][j] += xv.x * wv[j].x + xv.y * wv[j].y + xv.z * wv[j].z + xv.w * wv[j].w;
        }
    }
    __syncthreads();                               // done reading Xl -> reuse as transpose tile

    f16* Th = (f16*)Xl;            // [64 f][136 s]
    f16* Tl = Th + 64 * 136;
#pragma unroll
    for (int i = 0; i < 8; ++i) {
        int s = tx + 16 * i;
#pragma unroll
        for (int j = 0; j < 4; ++j) {
            float a = acc[i][j];
            f16 hh = (f16)a;
            Th[(f0 + j) * 136 + s] = hh;
            Tl[(f0 + j) * 136 + s] = (f16)(a - (float)hh);
        }
    }
    __syncthreads();

    for (int c = t; c < 1024; c += 256) {          // 64 e-rows x 128 s, uint4 = 8 f16
        int e = c >> 4, sc = (c & 15) << 3;
        size_t o = ((size_t)bh * 64 + e) * 2048 + sc0 + sc;
        *(uint4*)(Oh + o) = *(uint4*)&Th[e * 136 + sc];
        *(uint4*)(Ol + o) = *(uint4*)&Tl[e * 136 + sc];
    }
}

// ---------------- threefry2x32 (jax partitionable), key (0,42) — macro-inlined ----------------
// per flat i over [B,H,S,S]: (b1,b2)=threefry2x32((0,42),(0,i)); keep <=> (b1^b2) < 0xE6666600
#define QR2(r) \
    a0 += a1; b0 += b1; \
    a1 = __builtin_rotateleft32(a1, r); b1 = __builtin_rotateleft32(b1, r); \
    a1 ^= a0; b1 ^= b0;
#define TF4(p,q,rr,s) QR2(p) QR2(q) QR2(rr) QR2(s)
#define TF_FULL \
    TF4(13,15,26,6)   a0 += 42u;          a1 += 0x1BD11BF1u;  b0 += 42u;          b1 += 0x1BD11BF1u; \
    TF4(17,29,16,24)  a0 += 0x1BD11BF0u;  a1 += 2u;           b0 += 0x1BD11BF0u;  b1 += 2u; \
    TF4(13,15,26,6)                       a1 += 45u;                              b1 += 45u; \
    TF4(17,29,16,24)  a0 += 42u;          a1 += 0x1BD11BF4u;  b0 += 42u;          b1 += 0x1BD11BF4u; \
    TF4(13,15,26,6)   a0 += 0x1BD11BF0u;  a1 += 5u;           b0 += 0x1BD11BF0u;  b1 += 5u;

// 16 PRIVATE mask bits for this thread's own elements:
// rows qt*256 + w*16 + kg*4 + r (r=0..3), cols kt*64 + n*16 + lrow (n=0..3).
// bit index = n*4 + r. Chain a: bits 0..7 (n<2); chain b: bits 8..15 (n>=2, +32 cols).
#define MASK16(ktArg, dst) do { \
    u32 wm_ = 0u; \
    const u32 cb_ = ((u32)(bh * 2048 + qt * 256 + w * 16 + kg * 4) << 11) \
                  + (u32)(ktArg) * 64u + (u32)lrow + 42u; \
    _Pragma("unroll") \
    for (int j_ = 0; j_ < 8; ++j_) { \
        u32 a0 = 0u, a1 = cb_ + (u32)((j_ >> 2) * 16 + (j_ & 3) * 2048); \
        u32 b0 = 0u, b1 = a1 + 32u; \
        TF_FULL \
        wm_ |= ((a0 ^ a1) < 0xE6666600u) ? (1u << j_) : 0u; \
        wm_ |= ((b0 ^ b1) < 0xE6666600u) ? (1u << (j_ + 8)) : 0u; \
    } \
    (dst) = wm_; \
} while (0)

// identical score computation for both passes (bit-identical chain order per element)
#define COMPUTE_S(S, khp, klp) do { \
    _Pragma("unroll") for (int n = 0; n < 4; ++n) S[n] = f32x4v{0.f,0.f,0.f,0.f}; \
    _Pragma("unroll") for (int n = 0; n < 4; ++n) { \
        _Pragma("unroll") for (int ks = 0; ks < 2; ++ks) { \
            const int off_ = (n * 16 + lrow) * LDK + ks * 32 + kg * 8; \
            f16x8 bhf_ = *(const f16x8*)&(khp)[off_]; \
            f16x8 blf_ = *(const f16x8*)&(klp)[off_]; \
            S[n] = __builtin_amdgcn_mfma_f32_16x16x32_f16(qh[ks], bhf_, S[n], 0, 0, 0); \
            S[n] = __builtin_amdgcn_mfma_f32_16x16x32_f16(ql[ks], bhf_, S[n], 0, 0, 0); \
            S[n] = __builtin_amdgcn_mfma_f32_16x16x32_f16(qh[ks], blf_, S[n], 0, 0, 0); \
        } \
    } } while (0)

// grid (8, 32): x = 256-row Q tile, y = bh. 16 waves x 16 rows. 1 block/CU.
// MFMA 16x16x32 f16. A: A[m=lane&15][k=(lane>>4)*8+j]; B: B[k][n=lane&15];
// C: row=(lane>>4)*4+r, col=lane&15.
__global__ __launch_bounds__(1024, 4) void attn_kernel(
    const f16* __restrict__ Qh, const f16* __restrict__ Ql,
    const f16* __restrict__ Kh, const f16* __restrict__ Kl,
    const f16* __restrict__ Vth, const f16* __restrict__ Vtl,
    float* __restrict__ out)
{
    constexpr int LDK = 88;   // f16 stride: 176 B rows (16B aligned)
    __shared__ __align__(16) f16 kh_l[2][64 * LDK];   // double-buffered
    __shared__ __align__(16) f16 kl_l[2][64 * LDK];
    __shared__ __align__(16) f16 vh_l[2][64 * LDK];   // [e][s]
    __shared__ __align__(16) f16 vl_l[2][64 * LDK];
    __shared__ __align__(16) f16 p_l[16][16 * LDK];   // per-wave P tile (16 rows)

    const int t = threadIdx.x;
    const int w = t >> 6;
    const int lane = t & 63;
    const int lrow = lane & 15;
    const int kg = lane >> 4;
    const int qt = blockIdx.x;
    const int bh = blockIdx.y;

    // staging role: threads 0..511 -> K, 512..1023 -> V. One uint4 pair each.
    const int sc  = t & 511;
    const int sx  = sc >> 3;            // K row / V e-row
    const int sc8 = (sc & 7) << 3;
    const bool isK = (t < 512);

    // persistent Q fragments (hi/lo), one 16-row m-tile per wave, 2 k-steps
    f16x8 qh[2], ql[2];
    {
        size_t rowg = (size_t)bh * 2048 + qt * 256 + w * 16 + lrow;
        const f16* ph = Qh + rowg * 64 + kg * 8;
        const f16* pl = Ql + rowg * 64 + kg * 8;
        qh[0] = *(const f16x8*)(ph);
        qh[1] = *(const f16x8*)(ph + 32);
        ql[0] = *(const f16x8*)(pl);
        ql[1] = *(const f16x8*)(pl + 32);
    }

    const size_t kbase = (size_t)bh * 2048 * 64;   // same footprint for K and Vt

    // ---- pass A: row sums l = sum exp(s - 8); K only, double-buffered ----
    float lsum[4] = {0.f, 0.f, 0.f, 0.f};
    if (isK) {      // prologue: stage kt=0 into buf 0
        size_t g = kbase + (size_t)(sx * 64) + sc8;
        uint4 h4 = *(const uint4*)(Kh + g);
        uint4 l4 = *(const uint4*)(Kl + g);
        *(uint4*)&kh_l[0][sx * LDK + sc8] = h4;
        *(uint4*)&kl_l[0][sx * LDK + sc8] = l4;
    }
    __syncthreads();

    for (int kt = 0; kt < 32; ++kt) {
        const int cur = kt & 1;
        uint4 sA, sB;
        if (isK && kt < 31) {           // issue next tile's loads early
            size_t g = kbase + (size_t)((kt + 1) * 64 + sx) * 64 + sc8;
            sA = *(const uint4*)(Kh + g);
            sB = *(const uint4*)(Kl + g);
        }
        f32x4v sfr[4];
        COMPUTE_S(sfr, kh_l[cur], kl_l[cur]);
#pragma unroll
        for (int n = 0; n < 4; ++n)
#pragma unroll
            for (int r = 0; r < 4; ++r)
                lsum[r] += __expf(fmaf(sfr[n][r], 0.125f, -8.0f));
        if (isK && kt < 31) {           // commit after compute
            *(uint4*)&kh_l[cur ^ 1][sx * LDK + sc8] = sA;
            *(uint4*)&kl_l[cur ^ 1][sx * LDK + sc8] = sB;
        }
        __syncthreads();                // single barrier per kt
    }

    float rsc[4];
#pragma unroll
    for (int r = 0; r < 4; ++r) {
        float v = lsum[r];
        v += __shfl_xor(v, 1);
        v += __shfl_xor(v, 2);
        v += __shfl_xor(v, 4);
        v += __shfl_xor(v, 8);
        rsc[r] = 1.0f / (0.9f * v);   // folds dropout 1/(1-p)
    }

    // ---- pass B: recompute s, exact p, PRIVATE threefry dropout, fp16 cast, PV ----
    f32x4v oacc[4];
#pragma unroll
    for (int fn = 0; fn < 4; ++fn) oacc[fn] = f32x4v{0.f, 0.f, 0.f, 0.f};

    {   // prologue: stage kt=0 (K and V) into buf 0
        if (isK) {
            size_t g = kbase + (size_t)(sx * 64) + sc8;
            uint4 h4 = *(const uint4*)(Kh + g);
            uint4 l4 = *(const uint4*)(Kl + g);
            *(uint4*)&kh_l[0][sx * LDK + sc8] = h4;
            *(uint4*)&kl_l[0][sx * LDK + sc8] = l4;
        } else {
            size_t g = kbase + (size_t)sx * 2048 + sc8;
            uint4 h4 = *(const uint4*)(Vth + g);
            uint4 l4 = *(const uint4*)(Vtl + g);
            *(uint4*)&vh_l[0][sx * LDK + sc8] = h4;
            *(uint4*)&vl_l[0][sx * LDK + sc8] = l4;
        }
    }
    __syncthreads();

    for (int kt = 0; kt < 32; ++kt) {
        const int cur = kt & 1;
        uint4 sA, sB;
        if (kt < 31) {                  // issue next tile's loads early
            if (isK) {
                size_t g = kbase + (size_t)((kt + 1) * 64 + sx) * 64 + sc8;
                sA = *(const uint4*)(Kh + g);
                sB = *(const uint4*)(Kl + g);
            } else {
                size_t g = kbase + (size_t)sx * 2048 + (kt + 1) * 64 + sc8;
                sA = *(const uint4*)(Vth + g);
                sB = *(const uint4*)(Vtl + g);
            }
        }

        u32 pm;
        MASK16(kt, pm);                 // thread-private threefry (pure VALU)

        f32x4v sfr[4];
        COMPUTE_S(sfr, kh_l[cur], kl_l[cur]);

#pragma unroll
        for (int n = 0; n < 4; ++n)
#pragma unroll
            for (int r = 0; r < 4; ++r) {
                float e = __expf(fmaf(sfr[n][r], 0.125f, -8.0f));
                float p = e * rsc[r];
                if (!((pm >> (n * 4 + r)) & 1u)) p = 0.0f;
                p_l[w][(kg * 4 + r) * LDK + n * 16 + lrow] = (f16)p;  // RTNE = astype(f16)
            }

        // PV: out += P(16f exact) * (Vh + Vl)   (wave-private p_l: no barrier)
#pragma unroll
        for (int ks = 0; ks < 2; ++ks) {
            f16x8 pa0 = *(const f16x8*)&p_l[w][lrow * LDK + ks * 32 + kg * 8];
#pragma unroll
            for (int fn = 0; fn < 4; ++fn) {
                const int voff = (fn * 16 + lrow) * LDK + ks * 32 + kg * 8;
                f16x8 vhf = *(const f16x8*)&vh_l[cur][voff];
                f16x8 vlf = *(const f16x8*)&vl_l[cur][voff];
                oacc[fn] = __builtin_amdgcn_mfma_f32_16x16x32_f16(pa0, vhf, oacc[fn], 0, 0, 0);
                oacc[fn] = __builtin_amdgcn_mfma_f32_16x16x32_f16(pa0, vlf, oacc[fn], 0, 0, 0);
            }
        }

        if (kt < 31) {                  // commit after compute
            if (isK) {
                *(uint4*)&kh_l[cur ^ 1][sx * LDK + sc8] = sA;
                *(uint4*)&kl_l[cur ^ 1][sx * LDK + sc8] = sB;
            } else {
                *(uint4*)&vh_l[cur ^ 1][sx * LDK + sc8] = sA;
                *(uint4*)&vl_l[cur ^ 1][sx * LDK + sc8] = sB;
            }
        }
        __syncthreads();                // single barrier per kt
    }

    // epilogue: out [b,h,s,e] fp32
#pragma unroll
    for (int fn = 0; fn < 4; ++fn)
#pragma unroll
        for (int r = 0; r < 4; ++r) {
            int row = qt * 256 + w * 16 + kg * 4 + r;
            out[((size_t)bh * 2048 + row) * 64 + fn * 16 + lrow] = oacc[fn][r];
        }
}

extern "C" void kernel_launch(void* const* d_in, const int* in_sizes, int n_in,
                              void* d_out, int out_size, void* d_ws, size_t ws_size,
                              hipStream_t stream) {
    (void)in_sizes; (void)n_in; (void)out_size; (void)ws_size;
    const float* query = (const float*)d_in[0];
    const float* key_  = (const float*)d_in[1];
    const float* value = (const float*)d_in[2];
    const float* Wq = (const float*)d_in[3];
    const float* bq = (const float*)d_in[4];
    const float* Wk = (const float*)d_in[5];
    const float* bk = (const float*)d_in[6];
    const float* Wv = (const float*)d_in[7];
    const float* bv = (const float*)d_in[8];

    char* ws = (char*)d_ws;                 // needs 48 MiB
    f16* Qh  = (f16*)(ws);
    f16* Ql  = (f16*)(ws + 8388608);
    f16* Kh  = (f16*)(ws + 16777216);
    f16* Kl  = (f16*)(ws + 25165824);
    f16* Vth = (f16*)(ws + 33554432);
    f16* Vtl = (f16*)(ws + 41943040);

    proj_qk_kernel<<<512, 256, 0, stream>>>(query, Wq, bq, Qh, Ql);
    proj_qk_kernel<<<512, 256, 0, stream>>>(key_,  Wk, bk, Kh, Kl);
    proj_v_kernel<<<dim3(16, 32), 256, 0, stream>>>(value, Wv, bv, Vth, Vtl);
    attn_kernel<<<dim3(8, 32), 1024, 0, stream>>>(Qh, Ql, Kh, Kl, Vth, Vtl, (float*)d_out);
}